// Round 1
// 307.285 us; speedup vs baseline: 1.0322x; 1.0322x over previous
//
#include <hip/hip_runtime.h>

typedef float v2f __attribute__((ext_vector_type(2)));

#define BB 32
#define LL 32768
#define HH 32
#define NN2 8
#define NCOND 4
#define NCHUNK 256
#define LC (LL / NCHUNK)   // 128

// ws layout (floats):
//  PARAM_OFF: per h: [wr x8][wi x8][ctr x8][cti x8]   H*32  = 1024
//  WLC_OFF  : per (h,n): (wLc_r, wLc_i)               H*N2*2 = 512   (at 1024)
//  FILM_OFF : per (b,h): (gamma, beta)                B*H*2  = 2048  (at 1536)
//  S_OFF    : per flat=(b,c,h): [zr x8][zi x8]        B*H*NCHUNK*16  (at 4096)
//             pass_a writes chunk end-states; pass_b rewrites IN PLACE with
//             the exclusive prefix (chunk initial states); pass_c reads them.
#define PARAM_OFF 0
#define WLC_OFF   1024
#define FILM_OFF  1536
#define S_OFF     4096
#define SZ_S      (BB * HH * NCHUNK * 16)   // 4,194,304 floats -> ~16.8 MB total

static __device__ __forceinline__ v2f vfma(v2f a, v2f b, v2f c) {
  return __builtin_elementwise_fma(a, b, c);
}

__global__ void setup_kernel(const float* __restrict__ log_dt,
                             const float* __restrict__ C_re,
                             const float* __restrict__ C_im,
                             const float* __restrict__ log_A_real,
                             const float* __restrict__ A_imag,
                             const float* __restrict__ cond,
                             const float* __restrict__ film_W,
                             const float* __restrict__ film_b,
                             float* __restrict__ ws) {
  int idx = blockIdx.x * blockDim.x + threadIdx.x;
  if (idx < HH * NN2) {
    int h = idx >> 3, n = idx & (NN2 - 1);
    float dt = expf(log_dt[h]);
    float ar = -expf(log_A_real[idx]);
    float ai = A_imag[idx];
    float dr = ar * dt, di = ai * dt;        // dtA
    float er = expf(dr);
    float wr = er * cosf(di);
    float wi = er * sinf(di);
    // (exp(dtA)-1)/A
    float den = ar * ar + ai * ai;
    float tr = ((wr - 1.f) * ar + wi * ai) / den;
    float ti = (wi * ar - (wr - 1.f) * ai) / den;
    float cr = C_re[idx], ci = C_im[idx];
    float ctr = 2.f * (cr * tr - ci * ti);
    float cti = 2.f * (cr * ti + ci * tr);
    float* p = ws + PARAM_OFF + h * 32;
    p[n] = wr; p[n + 8] = wi; p[n + 16] = ctr; p[n + 24] = cti;
    // w^LC
    float eL  = expf(dr * (float)LC);
    float wlr = eL * cosf(di * (float)LC);
    float wli = eL * sinf(di * (float)LC);
    float* q = ws + WLC_OFF + idx * 2;
    q[0] = wlr; q[1] = wli;
  }
  int f = idx - HH * NN2;
  if (f >= 0 && f < BB * HH) {
    int b = f >> 5, h = f & (HH - 1);
    float g  = film_b[h];
    float be = film_b[h + HH];
    #pragma unroll
    for (int c2 = 0; c2 < NCOND; c2++) {
      float cv = cond[b * NCOND + c2];
      g  = fmaf(cv, film_W[c2 * 2 * HH + h], g);
      be = fmaf(cv, film_W[c2 * 2 * HH + HH + h], be);
    }
    float* p = ws + FILM_OFF + f * 2;
    p[0] = g; p[1] = be;
  }
}

__global__ __launch_bounds__(256) void pass_a(const float* __restrict__ x,
                                              float* __restrict__ ws) {
  const int flat = blockIdx.x * 256 + threadIdx.x;
  const int h = flat & (HH - 1);
  const int c = (flat >> 5) & (NCHUNK - 1);
  const int b = flat >> 13;
  const v2f* pp = (const v2f*)(ws + PARAM_OFF + h * 32);
  v2f wr[4], wi[4], zr[4], zi[4];
  #pragma unroll
  for (int g = 0; g < 4; g++) {
    wr[g] = pp[g]; wi[g] = pp[4 + g];
    zr[g] = (v2f){0.f, 0.f}; zi[g] = (v2f){0.f, 0.f};
  }
  const float* xp = x + ((size_t)b * LL + (size_t)c * LC) * HH + h;
  for (int i = 0; i < LC; i += 8) {
    float u[8];
    #pragma unroll
    for (int j = 0; j < 8; j++) u[j] = xp[(size_t)(i + j) * HH];
    #pragma unroll
    for (int j = 0; j < 8; j++) {
      v2f us = (v2f){u[j], u[j]};
      #pragma unroll
      for (int g = 0; g < 4; g++) {
        v2f t0  = vfma(-wi[g], zi[g], us);
        v2f nzr = vfma(wr[g], zr[g], t0);
        v2f nzi = vfma(wr[g], zi[g], wi[g] * zr[g]);
        zr[g] = nzr; zi[g] = nzi;
      }
    }
  }
  v2f* Sp = (v2f*)(ws + S_OFF + (size_t)flat * 16);
  #pragma unroll
  for (int g = 0; g < 4; g++) { Sp[g] = zr[g]; Sp[4 + g] = zi[g]; }
}

// Block-parallel chunk-prefix scan.
// One block of 256 threads per (b,h); thread t owns chunk c=t's 8 complex
// end-states (16 contiguous floats). Hillis-Steele inclusive scan of the
// constant-coefficient recurrence I_c = wLC * I_{c-1} + S_c (8 log-steps,
// multiplier squared each step), then write back the EXCLUSIVE prefix
// (I_{c-1}, 0 for c=0) in place — exactly what the old serial pass_b wrote.
__global__ __launch_bounds__(256) void pass_b(float* __restrict__ ws) {
  const int bh = blockIdx.x;            // 0 .. B*H-1
  const int b  = bh >> 5;
  const int h  = bh & (HH - 1);
  const int t  = threadIdx.x;           // chunk index

  __shared__ __align__(16) float Lbuf[NCHUNK][18];   // 16 payload + 2 pad

  float* Sp = ws + S_OFF +
              ((size_t)b * (NCHUNK * HH) + (size_t)t * HH + h) * 16;

  v2f zr[4], zi[4];
  #pragma unroll
  for (int g = 0; g < 4; g++) {
    zr[g] = ((const v2f*)Sp)[g];
    zi[g] = ((const v2f*)Sp)[4 + g];
  }

  // per-n multipliers wLC (n = 2g, 2g+1 packed into v2f lanes)
  const float* q = ws + WLC_OFF + h * NN2 * 2;
  v2f mr[4], mi[4];
  #pragma unroll
  for (int g = 0; g < 4; g++) {
    mr[g] = (v2f){q[4 * g + 0], q[4 * g + 2]};
    mi[g] = (v2f){q[4 * g + 1], q[4 * g + 3]};
  }

  v2f* rowv = (v2f*)&Lbuf[t][0];
  #pragma unroll
  for (int g = 0; g < 4; g++) { rowv[g] = zr[g]; rowv[4 + g] = zi[g]; }
  __syncthreads();

  #pragma unroll
  for (int d = 1; d < NCHUNK; d <<= 1) {
    v2f ar[4], ai[4];
    #pragma unroll
    for (int g = 0; g < 4; g++) { ar[g] = (v2f){0.f, 0.f}; ai[g] = (v2f){0.f, 0.f}; }
    if (t >= d) {
      const v2f* prow = (const v2f*)&Lbuf[t - d][0];
      #pragma unroll
      for (int g = 0; g < 4; g++) { ar[g] = prow[g]; ai[g] = prow[4 + g]; }
    }
    __syncthreads();   // all reads of old values done before overwrite
    #pragma unroll
    for (int g = 0; g < 4; g++) {
      zr[g] = vfma(mr[g], ar[g], vfma(-mi[g], ai[g], zr[g]));
      zi[g] = vfma(mr[g], ai[g], vfma(mi[g], ar[g], zi[g]));
      rowv[g] = zr[g]; rowv[4 + g] = zi[g];
      // multiplier := multiplier^2 (complex), using pre-update values
      v2f nmr = vfma(mr[g], mr[g], -(mi[g] * mi[g]));
      v2f nmi = (mr[g] + mr[g]) * mi[g];
      mr[g] = nmr; mi[g] = nmi;
    }
    __syncthreads();   // writes visible for next step's reads
  }

  // exclusive prefix: chunk c's initial state = inclusive[c-1]
  v2f er[4], ei[4];
  #pragma unroll
  for (int g = 0; g < 4; g++) { er[g] = (v2f){0.f, 0.f}; ei[g] = (v2f){0.f, 0.f}; }
  if (t > 0) {
    const v2f* prow = (const v2f*)&Lbuf[t - 1][0];
    #pragma unroll
    for (int g = 0; g < 4; g++) { er[g] = prow[g]; ei[g] = prow[4 + g]; }
  }
  #pragma unroll
  for (int g = 0; g < 4; g++) {
    ((v2f*)Sp)[g] = er[g];
    ((v2f*)Sp)[4 + g] = ei[g];
  }
}

__global__ __launch_bounds__(256) void pass_c(const float* __restrict__ x,
                                              const float* __restrict__ Dv,
                                              float* __restrict__ out,
                                              float* __restrict__ ws) {
  const int flat = blockIdx.x * 256 + threadIdx.x;
  const int h = flat & (HH - 1);
  const int c = (flat >> 5) & (NCHUNK - 1);
  const int b = flat >> 13;
  const v2f* pp = (const v2f*)(ws + PARAM_OFF + h * 32);
  v2f wr[4], wi[4], ctr[4], cti[4], zr[4], zi[4];
  #pragma unroll
  for (int g = 0; g < 4; g++) {
    wr[g] = pp[g]; wi[g] = pp[4 + g]; ctr[g] = pp[8 + g]; cti[g] = pp[12 + g];
  }
  const v2f* Zp = (const v2f*)(ws + S_OFF + (size_t)flat * 16);
  #pragma unroll
  for (int g = 0; g < 4; g++) { zr[g] = Zp[g]; zi[g] = Zp[4 + g]; }
  float gamma = ws[FILM_OFF + ((size_t)b * HH + h) * 2];
  float beta  = ws[FILM_OFF + ((size_t)b * HH + h) * 2 + 1];
  float dcoef = Dv[h];
  const size_t off = ((size_t)b * LL + (size_t)c * LC) * HH + h;
  const float* xp = x + off;
  float* op = out + off;
  for (int i = 0; i < LC; i += 8) {
    float u[8];
    #pragma unroll
    for (int j = 0; j < 8; j++) u[j] = xp[(size_t)(i + j) * HH];
    #pragma unroll
    for (int j = 0; j < 8; j++) {
      v2f us = (v2f){u[j], u[j]};
      v2f acc = (v2f){0.f, 0.f};
      #pragma unroll
      for (int g = 0; g < 4; g++) {
        v2f t0  = vfma(-wi[g], zi[g], us);
        v2f nzr = vfma(wr[g], zr[g], t0);
        v2f nzi = vfma(wr[g], zi[g], wi[g] * zr[g]);
        zr[g] = nzr; zi[g] = nzi;
        acc = vfma(ctr[g], nzr, acc);
        acc = vfma(-cti[g], nzi, acc);
      }
      float y = acc.x + acc.y;
      y = fmaf(dcoef, u[j], y);
      y = fmaf(gamma, y, beta);
      // tanh-approx gelu (JAX default approximate=True)
      float y3   = y * y * y;
      float targ = 0.7978845608f * fmaf(0.044715f, y3, y);
      float e    = __expf(2.f * targ);
      float th   = 1.f - __fdividef(2.f, e + 1.f);
      // out is write-only: nontemporal store, keep x resident in L3 instead
      __builtin_nontemporal_store(0.5f * y * (1.f + th),
                                  op + (size_t)(i + j) * HH);
    }
  }
}

extern "C" void kernel_launch(void* const* d_in, const int* in_sizes, int n_in,
                              void* d_out, int out_size, void* d_ws, size_t ws_size,
                              hipStream_t stream) {
  const float* x          = (const float*)d_in[0];
  const float* cond       = (const float*)d_in[1];
  const float* log_dt     = (const float*)d_in[2];
  const float* C_re       = (const float*)d_in[3];
  const float* C_im       = (const float*)d_in[4];
  const float* log_A_real = (const float*)d_in[5];
  const float* A_imag     = (const float*)d_in[6];
  const float* Dv         = (const float*)d_in[7];
  const float* film_W     = (const float*)d_in[8];
  const float* film_b     = (const float*)d_in[9];
  float* out = (float*)d_out;
  float* ws  = (float*)d_ws;

  setup_kernel<<<5, 256, 0, stream>>>(log_dt, C_re, C_im, log_A_real, A_imag,
                                      cond, film_W, film_b, ws);
  pass_a<<<(BB * HH * NCHUNK) / 256, 256, 0, stream>>>(x, ws);
  pass_b<<<BB * HH, 256, 0, stream>>>(ws);
  pass_c<<<(BB * HH * NCHUNK) / 256, 256, 0, stream>>>(x, Dv, out, ws);
}